// Round 3
// baseline (194.974 us; speedup 1.0000x reference)
//
#include <hip/hip_runtime.h>

// Problem constants (from reference): N=256, V=4, L=100000.
// out[n][v][l] = mask[n][l] ? (cats[n][l] == v ? 1 : 0) : s[n][v][l]
//
// Memory-bound elementwise select, ideal traffic 1.024 GB.
// R2: fix R1 compile error — __builtin_nontemporal_* needs clang
// ext_vector_type, not HIP_vector_type (int4/float4 structs).

#define N_SEQ 256
#define V_VOCAB 4
#define L_LEN 100000
#define LPT 8                    // l-positions per thread
#define L_CHUNKS (L_LEN / LPT)   // 12500, exact

typedef int   vint4   __attribute__((ext_vector_type(4)));
typedef float vfloat4 __attribute__((ext_vector_type(4)));

__global__ __launch_bounds__(256)
void mutate_kernel(const float* __restrict__ s,
                   const int* __restrict__ mask,
                   const int* __restrict__ cats,
                   float* __restrict__ out) {
    const int lc = blockIdx.x * blockDim.x + threadIdx.x;   // chunk index in L
    if (lc >= L_CHUNKS) return;
    const int n = blockIdx.y;

    const int l0 = lc * LPT;
    const long long nl = (long long)n * L_LEN + l0;

    const vint4 m0 = __builtin_nontemporal_load(reinterpret_cast<const vint4*>(mask + nl));
    const vint4 m1 = __builtin_nontemporal_load(reinterpret_cast<const vint4*>(mask + nl) + 1);
    const vint4 c0 = __builtin_nontemporal_load(reinterpret_cast<const vint4*>(cats + nl));
    const vint4 c1 = __builtin_nontemporal_load(reinterpret_cast<const vint4*>(cats + nl) + 1);

    #pragma unroll
    for (int v = 0; v < V_VOCAB; ++v) {
        const long long off = ((long long)n * V_VOCAB + v) * L_LEN + l0;
        const vfloat4 s0 = __builtin_nontemporal_load(reinterpret_cast<const vfloat4*>(s + off));
        const vfloat4 s1 = __builtin_nontemporal_load(reinterpret_cast<const vfloat4*>(s + off) + 1);
        vfloat4 o0, o1;
        #pragma unroll
        for (int j = 0; j < 4; ++j) {
            o0[j] = m0[j] ? (c0[j] == v ? 1.0f : 0.0f) : s0[j];
            o1[j] = m1[j] ? (c1[j] == v ? 1.0f : 0.0f) : s1[j];
        }
        __builtin_nontemporal_store(o0, reinterpret_cast<vfloat4*>(out + off));
        __builtin_nontemporal_store(o1, reinterpret_cast<vfloat4*>(out + off) + 1);
    }
}

extern "C" void kernel_launch(void* const* d_in, const int* in_sizes, int n_in,
                              void* d_out, int out_size, void* d_ws, size_t ws_size,
                              hipStream_t stream) {
    const float* s    = (const float*)d_in[0];   // (N, V, L) float32 one-hot
    const int*   mask = (const int*)d_in[1];     // (N, L) bool -> int32
    const int*   cats = (const int*)d_in[2];     // (N, L) int32
    float* out = (float*)d_out;                  // (N, V, L) float32

    const int block = 256;
    dim3 grid((L_CHUNKS + block - 1) / block, N_SEQ);   // (49, 256)
    mutate_kernel<<<grid, block, 0, stream>>>(s, mask, cats, out);
}